// Round 11
// baseline (430.670 us; speedup 1.0000x reference)
//
#include <hip/hip_runtime.h>
#include <hip/hip_fp16.h>

// Persistent 256-block kernel (1 block/CU forced by ~152 KB LDS).
// Rows 2b,2b+1 of all 64 Omega_t cached ONCE in LDS as fp16 (validated
// R4-R10, absmax 0.0078). NTAY=3 Taylor terms of expm(A)@v.
//
// Exchange: fence-free tagged-payload words (R7), 2 floats/word with tag in
// low-2 mantissa bits of float0 (R9/R10). R11: REPLICATED words -- publisher
// writes REP copies on REP distinct 64B lines; block b polls only replica
// b*REP/256. Pollers-per-line drops 256 -> 256/REP (R10 pm: pollers-per-word
// was never varied; write starvation of the publisher's store behind a
// saturated read stream is the ~5.4us/round floor candidate). Pure-spin poll
// (no s_sleep) for minimum detection latency. RBUF=2 rotating buffers
// (induction: pub(r+1) only after gather(r) => every block consumed r-1 =>
// distance-2 reuse safe; tag=(r>>1)&3, poison low2=2 != tag0).
// REP chosen from ws_size: 8 (256KB) -> 4 -> 2 -> 1 (64KB, known good).

#define NBLK 256
#define NTHR 512
#define NSTEP 20
#define NTAY 3
#define RBUF 2

typedef unsigned long long ull;

__device__ __forceinline__ float wredsum(float p) {
#pragma unroll
  for (int off = 32; off > 0; off >>= 1) p += __shfl_xor(p, off, 64);
  return p;
}

// line index of (buf, word, rep), each line 64 B = 8 ull
__device__ __forceinline__ ull* xw(ull* X, int buf, int word, int rep, int k) {
  return X + ((((buf << 8) + word) << k) + rep) * 8;
}

__device__ __forceinline__ void publishR(ull* X, int buf, int word, int k,
                                         float v0, float v1, unsigned int tag2) {
  unsigned int u0 = (__float_as_uint(v0) & ~3u) | tag2;
  ull x = (ull)u0 | ((ull)__float_as_uint(v1) << 32);
  const int nrep = 1 << k;
  for (int rp = 0; rp < nrep; ++rp)
    __hip_atomic_store(xw(X, buf, word, rp, k), x, __ATOMIC_RELAXED,
                       __HIP_MEMORY_SCOPE_AGENT);
}

__device__ __forceinline__ float2 pollR(ull* w, unsigned int tag2) {
  for (;;) {
    ull x = __hip_atomic_load(w, __ATOMIC_RELAXED, __HIP_MEMORY_SCOPE_AGENT);
    if ((unsigned int)(x & 3u) == tag2) {
      float2 r;
      r.x = __uint_as_float((unsigned int)x);
      r.y = __uint_as_float((unsigned int)(x >> 32));
      return r;
    }
  }
}

__global__ __launch_bounds__(NTHR) void petri_kernel(
    const float* __restrict__ vsrc, const float* __restrict__ vtgt,
    const float* __restrict__ omg,  const float* __restrict__ W1,
    const float* __restrict__ b1,   const float* __restrict__ W2,
    const float* __restrict__ b2,   const float* __restrict__ W3,
    const float* __restrict__ b3,   const float* __restrict__ gum,
    ull* __restrict__ X, float* __restrict__ out, int repk) {
  __shared__ __half2 oh[64 * 512];   // 128 KB: {row2b[j], row2b+1[j]} per t
  __shared__ float A0_s[512], A1_s[512];
  __shared__ float v_loc[512], tgt_s[512], w_s[512];
  __shared__ float w1c_s[1024];      // W1 column b (both halves)
  __shared__ float gum_s[NSTEP * 64];
  __shared__ float b2_s[128], b3_s[64];
  __shared__ float soft_s[64], h1_s[256], h2_s[128];
  __shared__ float redp[512];
  __shared__ float rf8[8];
  __shared__ int   ri8[8];
  __shared__ float acc2[2];
  __shared__ int   bc[1];

  const int b = blockIdx.x, tid = threadIdx.x;
  const int wv = tid >> 6, ln = tid & 63;
  const int myrep = (b << repk) >> 8;  // replica this block polls

  v_loc[tid] = vsrc[tid];
  tgt_s[tid] = vtgt[tid];
  w1c_s[tid] = W1[tid * 256 + b];
  w1c_s[tid + 512] = W1[(tid + 512) * 256 + b];
  for (int i = tid; i < NSTEP * 64; i += NTHR) gum_s[i] = gum[i];
  if (tid >= 512 - 128) {
    int j = tid - (512 - 128);
    b2_s[j] = b2[j];
    if (j < 64) b3_s[j] = b3[j];
  }
  // W2 slice in registers: thread (o=tid&127,q=tid>>7) holds W2[(q*64+i)*128+o]
  float w2r[64];
  {
    const int o = tid & 127, q = tid >> 7;
    const float* p = W2 + ((q << 6) * 128) + o;
#pragma unroll
    for (int i = 0; i < 64; ++i) w2r[i] = p[i * 128];
  }
  // W3 slice: thread (o=tid&63,q=tid>>6) holds W3[(q*16+i)*64+o]
  float w3r[16];
  {
    const int o = tid & 63, q = tid >> 6;
    const float* p = W3 + ((q << 4) * 64) + o;
#pragma unroll
    for (int i = 0; i < 16; ++i) w3r[i] = p[i * 64];
  }
  {
    const float* base0 = omg + (b << 10) + tid;  // row 2b of Omega_0, elem tid
#pragma unroll 4
    for (int t = 0; t < 64; ++t) {
      float x0 = base0[t * 262144];
      float x1 = base0[t * 262144 + 512];
      oh[t * 512 + tid] = __floats2half2_rn(x0, x1);
    }
  }
  __syncthreads();

  // target argmax (identical in every block), first-index tie-break
  int tgtIdx;
  {
    float v = tgt_s[tid]; int ix = tid;
#pragma unroll
    for (int off = 32; off > 0; off >>= 1) {
      float ov = __shfl_xor(v, off, 64); int oi = __shfl_xor(ix, off, 64);
      if (ov > v || (ov == v && oi < ix)) { v = ov; ix = oi; }
    }
    if (ln == 0) { rf8[wv] = v; ri8[wv] = ix; }
    __syncthreads();
    if (tid == 0) {
      float bv = rf8[0]; int bix = ri8[0];
      for (int q = 1; q < 8; ++q)
        if (rf8[q] > bv || (rf8[q] == bv && ri8[q] < bix)) { bv = rf8[q]; bix = ri8[q]; }
      bc[0] = bix;
    }
    __syncthreads();
    tgtIdx = bc[0];
    __syncthreads();
  }

  int d = 0;
  int r = 0;  // global round counter (uniform across blocks)

  for (int s = 0; s < NSTEP; ++s) {
    if (d) {  // frozen: zero logits row; no exchanges (uniform across blocks)
      if (b == 0 && tid < 64) out[512 + s * 64 + tid] = 0.0f;
      continue;
    }

    // ---- round: h1[b] = relu(dot(concat(v,tgt), W1[:,b]) + b1[b]) ----
    {
      const int buf = r & (RBUF - 1);
      const unsigned int tg = (unsigned int)((r >> 1) & 3);
      float p = fmaf(v_loc[tid], w1c_s[tid], tgt_s[tid] * w1c_s[tid + 512]);
      p = wredsum(p);
      if (ln == 0) rf8[wv] = p;
      __syncthreads();
      if (tid == 0) {
        float a = b1[b];
        for (int q = 0; q < 8; ++q) a += rf8[q];
        float h = fmaxf(a, 0.f);
        publishR(X, buf, b, repk, h, h, tg);
      }
      if (tid < 256) h1_s[tid] = pollR(xw(X, buf, tid, myrep, repk), tg).x;
      __syncthreads();
      ++r;
    }

    // ---- replicated L2/L3/softmax (register weights) ----
    {
      const int q = tid >> 7;
      float a = 0.f;
      const float* hp = h1_s + (q << 6);
#pragma unroll
      for (int i = 0; i < 64; ++i) a = fmaf(hp[i], w2r[i], a);
      redp[tid] = a;
    }
    __syncthreads();
    if (tid < 128) {
      float rr = redp[tid] + redp[tid + 128] + redp[tid + 256] + redp[tid + 384] + b2_s[tid];
      h2_s[tid] = fmaxf(rr, 0.f);
    }
    __syncthreads();
    {
      const int q = tid >> 6;
      float a = 0.f;
      const float* hp = h2_s + (q << 4);
#pragma unroll
      for (int i = 0; i < 16; ++i) a = fmaf(hp[i], w3r[i], a);
      redp[tid] = a;
    }
    __syncthreads();
    if (tid < 64) {
      float a = b3_s[tid];
#pragma unroll
      for (int q = 0; q < 8; ++q) a += redp[tid + (q << 6)];
      float lg = a + gum_s[s * 64 + tid];  // TAU = 1
      float mx = lg;
#pragma unroll
      for (int off = 32; off > 0; off >>= 1) mx = fmaxf(mx, __shfl_xor(mx, off, 64));
      float e = __expf(lg - mx);
      float sm = e;
#pragma unroll
      for (int off = 32; off > 0; off >>= 1) sm += __shfl_xor(sm, off, 64);
      soft_s[tid] = e / sm;
      if (b == 0) out[512 + s * 64 + tid] = a;  // pre-gumbel logits
    }
    __syncthreads();

    // ---- mix 2 rows of A from LDS fp16 ----
    {
      float a0 = 0.f, a1 = 0.f;
#pragma unroll 8
      for (int t = 0; t < 64; ++t) {
        float2 xy = __half22float2(oh[t * 512 + tid]);
        float sv = soft_s[t];
        a0 = fmaf(sv, xy.x, a0);
        a1 = fmaf(sv, xy.y, a1);
      }
      A0_s[tid] = a0; A1_s[tid] = a1;
    }
    __syncthreads();

    // ---- round: w1 = A v ----
    {
      const int buf = r & (RBUF - 1);
      const unsigned int tg = (unsigned int)((r >> 1) & 3);
      const float* Ar = (tid < 256) ? A0_s : A1_s;
      const int j = tid & 255;
      float p = fmaf(Ar[j], v_loc[j], Ar[j + 256] * v_loc[j + 256]);
      p = wredsum(p);
      if (ln == 0) rf8[wv] = p;
      __syncthreads();
      if (tid == 0) {
        float s0 = rf8[0] + rf8[1] + rf8[2] + rf8[3];
        float s1 = rf8[4] + rf8[5] + rf8[6] + rf8[7];
        acc2[0] = v_loc[(b << 1)] + s0;
        acc2[1] = v_loc[(b << 1) + 1] + s1;
        publishR(X, buf, b, repk, s0, s1, tg);
      }
      if (tid < 256) {
        float2 g = pollR(xw(X, buf, tid, myrep, repk), tg);
        w_s[(tid << 1)] = g.x;
        w_s[(tid << 1) + 1] = g.y;
      }
      __syncthreads();
      ++r;
    }

    // ---- rounds: Taylor n = 2..NTAY ; last publishes vnew ----
    for (int n = 2; n <= NTAY; ++n) {
      const int buf = r & (RBUF - 1);
      const unsigned int tg = (unsigned int)((r >> 1) & 3);
      const float* Ar = (tid < 256) ? A0_s : A1_s;
      const int j = tid & 255;
      float p = fmaf(Ar[j], w_s[j], Ar[j + 256] * w_s[j + 256]);
      p = wredsum(p);
      if (ln == 0) rf8[wv] = p;
      __syncthreads();
      if (tid == 0) {
        const float inv = 1.0f / (float)n;
        float s0 = (rf8[0] + rf8[1] + rf8[2] + rf8[3]) * inv;
        float s1 = (rf8[4] + rf8[5] + rf8[6] + rf8[7]) * inv;
        acc2[0] += s0; acc2[1] += s1;
        float p0 = (n < NTAY) ? s0 : acc2[0];
        float p1 = (n < NTAY) ? s1 : acc2[1];
        publishR(X, buf, b, repk, p0, p1, tg);
      }
      if (n < NTAY) {
        if (tid < 256) {
          float2 g = pollR(xw(X, buf, tid, myrep, repk), tg);
          w_s[(tid << 1)] = g.x;
          w_s[(tid << 1) + 1] = g.y;
        }
        __syncthreads();
        ++r;
      } else {
        // ---- gather vnew -> v_loc; carry + done check ----
        if (tid < 256) {
          float2 g = pollR(xw(X, buf, tid, myrep, repk), tg);
          v_loc[(tid << 1)] = g.x;
          v_loc[(tid << 1) + 1] = g.y;
        }
        __syncthreads();
        float v = v_loc[tid]; int ix = tid;
#pragma unroll
        for (int off = 32; off > 0; off >>= 1) {
          float ov = __shfl_xor(v, off, 64); int oi = __shfl_xor(ix, off, 64);
          if (ov > v || (ov == v && oi < ix)) { v = ov; ix = oi; }
        }
        if (ln == 0) { rf8[wv] = v; ri8[wv] = ix; }
        __syncthreads();
        if (tid == 0) {
          float bv = rf8[0]; int bix = ri8[0];
          for (int q = 1; q < 8; ++q)
            if (rf8[q] > bv || (rf8[q] == bv && ri8[q] < bix)) { bv = rf8[q]; bix = ri8[q]; }
          bc[0] = (bix == tgtIdx) ? 1 : 0;
        }
        __syncthreads();
        if (bc[0]) d = 1;
        __syncthreads();
        ++r;
      }
    }
  }

  // ---- epilogue: v_loc holds v_final ----
  if (b == 0) out[tid] = v_loc[tid];
}

extern "C" void kernel_launch(void* const* d_in, const int* in_sizes, int n_in,
                              void* d_out, int out_size, void* d_ws, size_t ws_size,
                              hipStream_t stream) {
  (void)in_sizes; (void)n_in; (void)out_size;
  // replica count from available scratch: need RBUF*256*(1<<k)*64 bytes
  int repk = 3;
  while (repk > 0 && (size_t)(RBUF * 256 * 64) * (size_t)(1 << repk) > ws_size)
    --repk;
  petri_kernel<<<dim3(NBLK), dim3(NTHR), 0, stream>>>(
      (const float*)d_in[0], (const float*)d_in[1], (const float*)d_in[2],
      (const float*)d_in[3], (const float*)d_in[4], (const float*)d_in[5],
      (const float*)d_in[6], (const float*)d_in[7], (const float*)d_in[8],
      (const float*)d_in[9], (ull*)d_ws, (float*)d_out, repk);
}